// Round 4
// baseline (7567.670 us; speedup 1.0000x reference)
//
#include <hip/hip_runtime.h>

typedef _Float16 f16;
typedef _Float16 f16x8 __attribute__((ext_vector_type(8)));
typedef _Float16 f16x4 __attribute__((ext_vector_type(4)));
typedef float    f32x4 __attribute__((ext_vector_type(4)));

#define N_   8
#define C_   256
#define H_   128
#define W_   128
#define K_   9
#define PAD_ 4
#define WP_  136            // padded w rows: wp = w + 4, rows 0..135, pads zeroed

#define WELEMS (16*9*8*64*8)        // 589824 = C_*C_*K_ fragment-linear
#define XT_SZ  (N_*WP_*C_)          // 278528 f16 per (buf, hi/lo)
#define NBLK   256
#define NSTEP  253

// swizzled f16 offset within a 256-f16 X row (granule = 8 f16 = 16B; XOR row&7)
__device__ inline int xswz(int ci, int wp) {
    return (((ci >> 3) ^ (wp & 7)) << 3) | (ci & 7);
}

// ---------------- weight prep: fragment-linear fp16 hi/lo ----------------
// t = (((ct*9 + k)*8 + cic)*64 + lane)*8 + j ; co = ct*16+(lane&15); ci = cic*32+(lane>>4)*8+j
__global__ __launch_bounds__(256) void prep_w(const float* __restrict__ w,
                                              f16* __restrict__ wh, f16* __restrict__ wl) {
    int t = blockIdx.x * 256 + threadIdx.x;
    if (t >= WELEMS) return;
    int j = t & 7;      int idx = t >> 3;
    int lane = idx & 63; idx >>= 6;
    int cic = idx & 7;   idx >>= 3;
    int k = idx % 9;     int ct = idx / 9;
    int co = ct * 16 + (lane & 15);
    int ci = cic * 32 + (lane >> 4) * 8 + j;
    float wf = w[(co * C_ + ci) * K_ + k];
    f16 hi = (f16)wf;
    f16 lo = (f16)(wf - (float)hi);
    wh[t] = hi;  wl[t] = lo;
}

// ---------------- Xt init: buf0 = fea row0 (swizzled hi/lo), zero pads of both bufs ----------------
__global__ __launch_bounds__(256) void prep_x0(const float* __restrict__ fea,
                                               f16* __restrict__ x0h, f16* __restrict__ x0l,
                                               f16* __restrict__ x1h, f16* __restrict__ x1l) {
    int t = blockIdx.x * 256 + threadIdx.x;
    if (t >= XT_SZ) return;
    int ci = t & 255;
    int wp = (t >> 8) % WP_;
    int n  = t / (WP_ * 256);
    int w  = wp - PAD_;
    bool pad = (unsigned)w >= (unsigned)W_;
    float v = pad ? 0.0f : fea[((size_t)(n * C_ + ci) * H_ + 0) * W_ + w];
    f16 hi = (f16)v;
    f16 lo = (f16)(v - (float)hi);
    size_t dst = ((size_t)n * WP_ + wp) * C_ + xswz(ci, wp);
    x0h[dst] = hi;  x0l[dst] = lo;
    if (pad) { x1h[dst] = (f16)0.f; x1l[dst] = (f16)0.f; }
}

// ---------------- out row0 = fea row0 ----------------
__global__ __launch_bounds__(256) void copy_row0(const float* __restrict__ fea,
                                                 float* __restrict__ out) {
    int idx = blockIdx.x * 256 + threadIdx.x;
    if (idx >= N_ * C_ * W_) return;
    int w = idx % W_;
    int nc = idx / W_;
    size_t off = (size_t)nc * (H_ * W_) + w;
    out[off] = fea[off];
}

// ---------------- persistent scan kernel ----------------
// 256 blocks x 512 threads, 1 block/CU, all co-resident. Block b: n=b&7 (XCD-local X),
// ct=(b>>3)&15 (16 co), whf=b>>7 (w half). Wave wi owns ci-chunk wi (32 ci), w-subtile wi&3.
__global__ __launch_bounds__(512, 2) void conv_persist(
    f16* __restrict__ x0h, f16* __restrict__ x0l,
    f16* __restrict__ x1h, f16* __restrict__ x1l,
    const f16* __restrict__ whp, const f16* __restrict__ wlp,
    const float* __restrict__ bias, const float* __restrict__ fea,
    float* out, unsigned* ctr)
{
    __shared__ alignas(16) unsigned char Xs[72 * 512];   // 36 KB, aliased as red[] later
    f32x4* red = (f32x4*)Xs;

    const int b   = blockIdx.x;
    const int n   = b & 7;
    const int ct  = (b >> 3) & 15;
    const int whf = b >> 7;
    const int w0  = whf * 64;
    const int wi  = threadIdx.x >> 6;
    const int l   = threadIdx.x & 63;

    // ---- weights -> VGPR, once ----
    f16x8 wk_h[9], wk_l[9];
    #pragma unroll
    for (int k = 0; k < 9; ++k) {
        size_t o = ((((size_t)ct * 9 + k) * 8 + wi) * 64 + l) * 8;
        wk_h[k] = *(const f16x8*)&whp[o];
        wk_l[k] = *(const f16x8*)&wlp[o];
    }

    f16* bufh[2] = {x0h, x1h};
    f16* bufl[2] = {x0l, x1l};

    const int gcol = (wi * 4 + (l >> 4)) << 4;   // byte granule base within a 512B row
    const int co0  = ct * 16 + (l >> 4) * 4;
    const int wsub = wi & 3;
    const int wcol = w0 + wsub * 16 + (l & 15);

    for (int step = 0; step < NSTEP; ++step) {
        const int  cur   = step & 1;
        const bool fwd   = step < 127;
        const int  h_out = fwd ? (step + 1) : (NSTEP - step);
        const float* radd = fwd ? fea : out;

        const char* gH = (const char*)(bufh[cur] + ((size_t)n * WP_ + w0) * C_);
        const char* gL = (const char*)(bufl[cur] + ((size_t)n * WP_ + w0) * C_);

        // ---- stage hi half (36 KB, pre-swizzled global -> linear LDS) ----
        #pragma unroll
        for (int t = 0; t < 5; ++t) {
            int i = wi + t * 8;
            if (i < 36)
                __builtin_amdgcn_global_load_lds(
                    (const __attribute__((address_space(1))) void*)(gH + i * 1024 + l * 16),
                    (__attribute__((address_space(3))) void*)(Xs + i * 1024), 16, 0, 0);
        }
        asm volatile("s_waitcnt vmcnt(0)" ::: "memory");
        __syncthreads();

        f32x4 accA[4] = {{0,0,0,0},{0,0,0,0},{0,0,0,0},{0,0,0,0}};  // Wh*Xh (+Wh*Xl later)
        f32x4 accB[4] = {{0,0,0,0},{0,0,0,0},{0,0,0,0},{0,0,0,0}};  // Wl*Xh
        #pragma unroll
        for (int k = 0; k < 9; ++k) {
            #pragma unroll
            for (int ws2 = 0; ws2 < 4; ++ws2) {
                int r = ws2 * 16 + (l & 15) + k;
                f16x8 bf = *(const f16x8*)(Xs + r * 512 + (gcol ^ ((r & 7) << 4)));
                accA[ws2] = __builtin_amdgcn_mfma_f32_16x16x32_f16(wk_h[k], bf, accA[ws2], 0, 0, 0);
                accB[ws2] = __builtin_amdgcn_mfma_f32_16x16x32_f16(wk_l[k], bf, accB[ws2], 0, 0, 0);
            }
        }
        __syncthreads();

        // ---- stage lo half into same LDS ----
        #pragma unroll
        for (int t = 0; t < 5; ++t) {
            int i = wi + t * 8;
            if (i < 36)
                __builtin_amdgcn_global_load_lds(
                    (const __attribute__((address_space(1))) void*)(gL + i * 1024 + l * 16),
                    (__attribute__((address_space(3))) void*)(Xs + i * 1024), 16, 0, 0);
        }
        asm volatile("s_waitcnt vmcnt(0)" ::: "memory");
        __syncthreads();

        #pragma unroll
        for (int k = 0; k < 9; ++k) {
            #pragma unroll
            for (int ws2 = 0; ws2 < 4; ++ws2) {
                int r = ws2 * 16 + (l & 15) + k;
                f16x8 bf = *(const f16x8*)(Xs + r * 512 + (gcol ^ ((r & 7) << 4)));
                accA[ws2] = __builtin_amdgcn_mfma_f32_16x16x32_f16(wk_h[k], bf, accA[ws2], 0, 0, 0);
            }
        }
        __syncthreads();          // Xs dead -> reuse as red

        // ---- cross-wave ci reduction (8 partials) ----
        #pragma unroll
        for (int ws2 = 0; ws2 < 4; ++ws2)
            red[(wi * 4 + ws2) * 64 + l] = accA[ws2] + accB[ws2];
        __syncthreads();

        f32x4 s = red[wsub * 64 + l];
        #pragma unroll
        for (int j = 1; j < 8; ++j) s += red[(j * 4 + wsub) * 64 + l];

        // ---- epilogue: y = relu(s + bias) + radd ----
        float4 bv = *(const float4*)&bias[co0];
        const size_t obase = (((size_t)(n * C_ + co0)) * H_ + h_out) * W_ + wcol;
        float y[4];
        #pragma unroll
        for (int r2 = 0; r2 < 4; ++r2) {
            float v = fmaxf(s[r2] + ((const float*)&bv)[r2], 0.0f)
                    + radd[obase + (size_t)r2 * (H_ * W_)];
            y[r2] = v;
        }
        if (wi < 4) {             // waves 0-3: fp32 out
            #pragma unroll
            for (int r2 = 0; r2 < 4; ++r2)
                out[obase + (size_t)r2 * (H_ * W_)] = y[r2];
        } else {                  // waves 4-7: swizzled hi/lo X for next step
            const int wp = wcol + PAD_;
            const size_t xo = ((size_t)n * WP_ + wp) * C_ + xswz(co0, wp);
            f16x4 hv, lv;
            #pragma unroll
            for (int r2 = 0; r2 < 4; ++r2) {
                f16 hi = (f16)y[r2];
                hv[r2] = hi;
                lv[r2] = (f16)(y[r2] - (float)hi);
            }
            *(f16x4*)&bufh[cur ^ 1][xo] = hv;
            *(f16x4*)&bufl[cur ^ 1][xo] = lv;
        }

        // ---- grid barrier (agent scope; release our stores, acquire others') ----
        __syncthreads();
        if (threadIdx.x == 0) {
            __hip_atomic_fetch_add(ctr, 1u, __ATOMIC_ACQ_REL, __HIP_MEMORY_SCOPE_AGENT);
            const unsigned tgt = (unsigned)NBLK * (unsigned)(step + 1);
            while (__hip_atomic_load(ctr, __ATOMIC_ACQUIRE, __HIP_MEMORY_SCOPE_AGENT) < tgt)
                __builtin_amdgcn_s_sleep(1);
        }
        __syncthreads();
    }
}

// ---------------- fallback (ws too small): fp32 per-step kernels ----------------
__global__ __launch_bounds__(256) void step_f32(
    const float* __restrict__ xprev, const float* __restrict__ radd,
    float* __restrict__ yout, const float* __restrict__ wsrc,
    const float* __restrict__ bias, int h_prev, int h_out)
{
    __shared__ float XsF[C_][40];
    const int t  = threadIdx.x;
    const int bx = blockIdx.x;
    const int n  = bx & 7;
    const int wb = (bx >> 3) & 3;
    const int cb = bx >> 5;
    const int w0 = wb * 32;
    {
        const size_t nbase = (size_t)n * C_ * (H_ * W_) + (size_t)h_prev * W_;
        for (int idx = t; idx < C_ * 40; idx += 256) {
            int ci = idx / 40;
            int j  = idx - ci * 40;
            int w  = w0 - PAD_ + j;
            float v = 0.0f;
            if ((unsigned)w < (unsigned)W_)
                v = xprev[nbase + (size_t)ci * (H_ * W_) + w];
            XsF[ci][j] = v;
        }
    }
    __syncthreads();
    const int co = cb * 32 + (t >> 3);
    const int w4 = (t & 7) * 4;
    const float* wr = wsrc + (size_t)co * (C_ * K_);
    float acc0 = 0.f, acc1 = 0.f, acc2 = 0.f, acc3 = 0.f;
    for (int ci = 0; ci < C_; ci++) {
        float wk[K_];
        #pragma unroll
        for (int k = 0; k < K_; k++) wk[k] = wr[ci * K_ + k];
        float xv[12];
        float4 a = *(const float4*)&XsF[ci][w4];
        float4 bq = *(const float4*)&XsF[ci][w4 + 4];
        float4 c = *(const float4*)&XsF[ci][w4 + 8];
        xv[0]=a.x; xv[1]=a.y; xv[2]=a.z; xv[3]=a.w;
        xv[4]=bq.x; xv[5]=bq.y; xv[6]=bq.z; xv[7]=bq.w;
        xv[8]=c.x; xv[9]=c.y; xv[10]=c.z; xv[11]=c.w;
        #pragma unroll
        for (int k = 0; k < K_; k++) {
            acc0 = fmaf(wk[k], xv[k],     acc0);
            acc1 = fmaf(wk[k], xv[k + 1], acc1);
            acc2 = fmaf(wk[k], xv[k + 2], acc2);
            acc3 = fmaf(wk[k], xv[k + 3], acc3);
        }
    }
    const float bb = bias[co];
    const size_t obase = (((size_t)n * C_ + co) * H_ + h_out) * W_ + w0 + w4;
    float4 r = *(const float4*)&radd[obase];
    float4 o;
    o.x = fmaxf(acc0 + bb, 0.f) + r.x;
    o.y = fmaxf(acc1 + bb, 0.f) + r.y;
    o.z = fmaxf(acc2 + bb, 0.f) + r.z;
    o.w = fmaxf(acc3 + bb, 0.f) + r.w;
    *(float4*)&yout[obase] = o;
}

extern "C" void kernel_launch(void* const* d_in, const int* in_sizes, int n_in,
                              void* d_out, int out_size, void* d_ws, size_t ws_size,
                              hipStream_t stream) {
    const float* fea    = (const float*)d_in[0];
    const float* weight = (const float*)d_in[1];
    const float* bias   = (const float*)d_in[2];
    float* out = (float*)d_out;

    // ws: Wh | Wl | x0h | x0l | x1h | x1l | ctr
    const size_t need = (size_t)2 * WELEMS * 2 + (size_t)4 * XT_SZ * 2 + 256;

    copy_row0<<<(N_ * C_ * W_ + 255) / 256, 256, 0, stream>>>(fea, out);

    if (ws_size >= need && d_ws != nullptr) {
        f16* wh  = (f16*)d_ws;
        f16* wl  = wh + WELEMS;
        f16* x0h = wl + WELEMS;
        f16* x0l = x0h + XT_SZ;
        f16* x1h = x0l + XT_SZ;
        f16* x1l = x1h + XT_SZ;
        unsigned* ctr = (unsigned*)(x1l + XT_SZ);

        hipMemsetAsync(ctr, 0, sizeof(unsigned), stream);
        prep_w<<<(WELEMS + 255) / 256, 256, 0, stream>>>(weight, wh, wl);
        prep_x0<<<(XT_SZ + 255) / 256, 256, 0, stream>>>(fea, x0h, x0l, x1h, x1l);

        conv_persist<<<NBLK, 512, 0, stream>>>(x0h, x0l, x1h, x1l, wh, wl,
                                               bias, fea, out, ctr);
    } else {
        for (int h = 1; h < H_; h++)
            step_f32<<<256, 256, 0, stream>>>(out, fea, out, weight, bias, h - 1, h);
        for (int h = H_ - 2; h >= 1; h--)
            step_f32<<<256, 256, 0, stream>>>(out, out, out, weight, bias, h + 1, h);
    }
}

// Round 6
// 1895.561 us; speedup vs baseline: 3.9923x; 3.9923x over previous
//
#include <hip/hip_runtime.h>

typedef _Float16 f16;
typedef _Float16 f16x8 __attribute__((ext_vector_type(8)));
typedef _Float16 f16x4 __attribute__((ext_vector_type(4)));
typedef float    f32x4 __attribute__((ext_vector_type(4)));
typedef unsigned long long u64;

#define N_   8
#define C_   256
#define H_   128
#define W_   128
#define K_   9
#define PAD_ 4
#define WP_  136            // padded w rows: wp = w + 4, rows 0..135, pads zeroed

#define WELEMS (16*9*8*64*8)        // 589824 = C_*C_*K_ fragment-linear
#define XT_SZ  (N_*WP_*C_)          // 278528 f16 per (buf, hi/lo)
#define NBLK   256
#define NSTEP  253
#define LDS_BYTES (72 * 1024)       // 72 rows x (512B hi | 512B lo)

// swizzled f16 offset within a 256-f16 X row (granule = 8 f16 = 16B; XOR wp&7)
__device__ __host__ inline int xswz(int ci, int wp) {
    return (((ci >> 3) ^ (wp & 7)) << 3) | (ci & 7);
}

// ---------------- weight prep: fragment-linear fp16 hi/lo ----------------
// t = (((ct*9 + k)*8 + cic)*64 + lane)*8 + j ; co = ct*16+(lane&15); ci = cic*32+(lane>>4)*8+j
__global__ __launch_bounds__(256) void prep_w(const float* __restrict__ w,
                                              f16* __restrict__ wh, f16* __restrict__ wl) {
    int t = blockIdx.x * 256 + threadIdx.x;
    if (t >= WELEMS) return;
    int j = t & 7;      int idx = t >> 3;
    int lane = idx & 63; idx >>= 6;
    int cic = idx & 7;   idx >>= 3;
    int k = idx % 9;     int ct = idx / 9;
    int co = ct * 16 + (lane & 15);
    int ci = cic * 32 + (lane >> 4) * 8 + j;
    float wf = w[(co * C_ + ci) * K_ + k];
    f16 hi = (f16)wf;
    f16 lo = (f16)(wf - (float)hi);
    wh[t] = hi;  wl[t] = lo;
}

// ---------------- Xt init: buf0 = fea row0 (swizzled hi/lo), zero pads of both bufs ----------------
__global__ __launch_bounds__(256) void prep_x0(const float* __restrict__ fea,
                                               f16* __restrict__ x0h, f16* __restrict__ x0l,
                                               f16* __restrict__ x1h, f16* __restrict__ x1l) {
    int t = blockIdx.x * 256 + threadIdx.x;
    if (t >= XT_SZ) return;
    int ci = t & 255;
    int wp = (t >> 8) % WP_;
    int n  = t / (WP_ * 256);
    int w  = wp - PAD_;
    bool pad = (unsigned)w >= (unsigned)W_;
    float v = pad ? 0.0f : fea[((size_t)(n * C_ + ci) * H_ + 0) * W_ + w];
    f16 hi = (f16)v;
    f16 lo = (f16)(v - (float)hi);
    size_t dst = ((size_t)n * WP_ + wp) * C_ + xswz(ci, wp);
    x0h[dst] = hi;  x0l[dst] = lo;
    if (pad) { x1h[dst] = (f16)0.f; x1l[dst] = (f16)0.f; }
}

// ---------------- out row0 = fea row0 ----------------
__global__ __launch_bounds__(256) void copy_row0(const float* __restrict__ fea,
                                                 float* __restrict__ out) {
    int idx = blockIdx.x * 256 + threadIdx.x;
    if (idx >= N_ * C_ * W_) return;
    int w = idx % W_;
    int nc = idx / W_;
    size_t off = (size_t)nc * (H_ * W_) + w;
    out[off] = fea[off];
}

// ---------------- persistent scan kernel ----------------
// 256 blocks x 512 threads. Block b: n=b&7, ct=(b>>3)&15, whf=b>>7.
// Wave wi owns ci-chunk wi (32 ci); epilogue duty split: wi<4 -> out, wi>=4 -> X.
// Cross-block X traffic via relaxed AGENT atomics (sc1 -> IF$-coherent); per-n relaxed barrier.
__global__ __launch_bounds__(512, 2) void conv_persist(
    f16* __restrict__ x0h, f16* __restrict__ x0l,
    f16* __restrict__ x1h, f16* __restrict__ x1l,
    const f16* __restrict__ whp, const f16* __restrict__ wlp,
    const float* __restrict__ bias, const float* __restrict__ fea,
    float* out, unsigned* ctr)
{
    extern __shared__ unsigned char Xs[];        // 72 KB; reused as red[] after compute
    f32x4* red = (f32x4*)Xs;

    const int b   = blockIdx.x;
    const int n   = b & 7;
    const int ct  = (b >> 3) & 15;
    const int whf = b >> 7;
    const int w0  = whf * 64;
    const int wi  = threadIdx.x >> 6;
    const int l   = threadIdx.x & 63;
    unsigned* gc  = ctr + n * 64;                // per-n counter, own cacheline

    // ---- weights -> VGPR, once ----
    f16x8 wk_h[9], wk_l[9];
    #pragma unroll
    for (int k = 0; k < 9; ++k) {
        size_t o = ((((size_t)ct * 9 + k) * 8 + wi) * 64 + l) * 8;
        wk_h[k] = *(const f16x8*)&whp[o];
        wk_l[k] = *(const f16x8*)&wlp[o];
    }

    f16* bufh[2] = {x0h, x1h};
    f16* bufl[2] = {x0l, x1l};

    const int gcol = (wi * 4 + (l >> 4)) << 4;   // byte granule base within 512B half-row
    const int co0  = ct * 16 + (l >> 4) * 4;
    const int wsub = wi & 3;
    const int wcol = w0 + wsub * 16 + (l & 15);
    float4 bv = *(const float4*)&bias[co0];

    for (int step = 0; step < NSTEP; ++step) {
        const int  cur   = step & 1;
        const bool fwd   = step < 127;
        const int  h_out = fwd ? (step + 1) : (NSTEP - step);
        const float* radd = fwd ? fea : out;
        const size_t obase = (((size_t)(n * C_ + co0)) * H_ + h_out) * W_ + wcol;

        // ---- stage X (hi|lo) into LDS via coherent (IF$) loads ----
        {
            const u64* gh = (const u64*)(bufh[cur] + ((size_t)n * WP_ + w0) * C_);
            const u64* gl = (const u64*)(bufl[cur] + ((size_t)n * WP_ + w0) * C_);
            #pragma unroll
            for (int ii = 0; ii < 9; ++ii) {
                int i = (int)threadIdx.x + ii * 512;
                int row = i >> 6, g = i & 63;
                // one X row = 256 f16 = 64 u64 (R5 bug: used stride 32)
                u64 hv = __hip_atomic_load(gh + row * 64 + g, __ATOMIC_RELAXED, __HIP_MEMORY_SCOPE_AGENT);
                u64 lv = __hip_atomic_load(gl + row * 64 + g, __ATOMIC_RELAXED, __HIP_MEMORY_SCOPE_AGENT);
                *(u64*)(Xs + row * 1024 +       g * 8) = hv;
                *(u64*)(Xs + row * 1024 + 512 + g * 8) = lv;
            }
        }
        // prefetch this step's radd (plain cached loads; latency hides under compute)
        float rv[4];
        #pragma unroll
        for (int r2 = 0; r2 < 4; ++r2)
            rv[r2] = radd[obase + (size_t)r2 * (H_ * W_)];
        __syncthreads();

        // ---- compute: 9k x 4 quadrants x 3 products ----
        f32x4 a0[4] = {{0,0,0,0},{0,0,0,0},{0,0,0,0},{0,0,0,0}};  // Wh*Xh
        f32x4 a1[4] = {{0,0,0,0},{0,0,0,0},{0,0,0,0},{0,0,0,0}};  // Wh*Xl
        f32x4 a2[4] = {{0,0,0,0},{0,0,0,0},{0,0,0,0},{0,0,0,0}};  // Wl*Xh
        #pragma unroll
        for (int k = 0; k < 9; ++k) {
            #pragma unroll
            for (int q = 0; q < 4; ++q) {
                int r = q * 16 + (l & 15) + k;
                const unsigned char* base = Xs + r * 1024 + (gcol ^ ((r & 7) << 4));
                f16x8 bh = *(const f16x8*)base;
                f16x8 bl = *(const f16x8*)(base + 512);
                a0[q] = __builtin_amdgcn_mfma_f32_16x16x32_f16(wk_h[k], bh, a0[q], 0, 0, 0);
                a1[q] = __builtin_amdgcn_mfma_f32_16x16x32_f16(wk_h[k], bl, a1[q], 0, 0, 0);
                a2[q] = __builtin_amdgcn_mfma_f32_16x16x32_f16(wk_l[k], bh, a2[q], 0, 0, 0);
            }
        }
        __syncthreads();          // Xs dead -> reuse as red

        // ---- cross-wave ci reduction (8 partials per (quadrant, lane)) ----
        #pragma unroll
        for (int q = 0; q < 4; ++q)
            red[(wi * 4 + q) * 64 + l] = (a0[q] + a1[q]) + a2[q];
        __syncthreads();

        f32x4 s = red[wsub * 64 + l];
        #pragma unroll
        for (int j = 1; j < 8; ++j) s += red[(j * 4 + wsub) * 64 + l];

        // ---- epilogue: y = relu(s + bias) + radd ----
        float y[4];
        #pragma unroll
        for (int r2 = 0; r2 < 4; ++r2)
            y[r2] = fmaxf(s[r2] + ((const float*)&bv)[r2], 0.0f) + rv[r2];

        if (wi < 4) {             // waves 0-3: fp32 out (plain, L2)
            #pragma unroll
            for (int r2 = 0; r2 < 4; ++r2)
                out[obase + (size_t)r2 * (H_ * W_)] = y[r2];
        } else {                  // waves 4-7: swizzled hi/lo X -> IF$-coherent stores
            const int wp = wcol + PAD_;
            const size_t xo = ((size_t)n * WP_ + wp) * C_ + xswz(co0, wp);
            f16x4 hv, lv;
            #pragma unroll
            for (int r2 = 0; r2 < 4; ++r2) {
                f16 hi = (f16)y[r2];
                hv[r2] = hi;
                lv[r2] = (f16)(y[r2] - (float)hi);
            }
            u64 uh, ul;
            __builtin_memcpy(&uh, &hv, 8);
            __builtin_memcpy(&ul, &lv, 8);
            __hip_atomic_store((u64*)&bufh[cur ^ 1][xo], uh, __ATOMIC_RELAXED, __HIP_MEMORY_SCOPE_AGENT);
            __hip_atomic_store((u64*)&bufl[cur ^ 1][xo], ul, __ATOMIC_RELAXED, __HIP_MEMORY_SCOPE_AGENT);
        }

        // ---- per-n relaxed barrier (32 blocks; no cache maintenance) ----
        if (step < NSTEP - 1) {
            asm volatile("s_waitcnt vmcnt(0)" ::: "memory");   // every wave drains its X stores
            __syncthreads();
            if (threadIdx.x == 0) {
                __hip_atomic_fetch_add(gc, 1u, __ATOMIC_RELAXED, __HIP_MEMORY_SCOPE_AGENT);
                const unsigned tgt = 32u * (unsigned)(step + 1);
                while (__hip_atomic_load(gc, __ATOMIC_RELAXED, __HIP_MEMORY_SCOPE_AGENT) < tgt)
                    __builtin_amdgcn_s_sleep(2);
            }
            __syncthreads();
        }
    }
}

// ---------------- fallback (ws too small): fp32 per-step kernels ----------------
__global__ __launch_bounds__(256) void step_f32(
    const float* __restrict__ xprev, const float* __restrict__ radd,
    float* __restrict__ yout, const float* __restrict__ wsrc,
    const float* __restrict__ bias, int h_prev, int h_out)
{
    __shared__ float XsF[C_][40];
    const int t  = threadIdx.x;
    const int bx = blockIdx.x;
    const int n  = bx & 7;
    const int wb = (bx >> 3) & 3;
    const int cb = bx >> 5;
    const int w0 = wb * 32;
    {
        const size_t nbase = (size_t)n * C_ * (H_ * W_) + (size_t)h_prev * W_;
        for (int idx = t; idx < C_ * 40; idx += 256) {
            int ci = idx / 40;
            int j  = idx - ci * 40;
            int w  = w0 - PAD_ + j;
            float v = 0.0f;
            if ((unsigned)w < (unsigned)W_)
                v = xprev[nbase + (size_t)ci * (H_ * W_) + w];
            XsF[ci][j] = v;
        }
    }
    __syncthreads();
    const int co = cb * 32 + (t >> 3);
    const int w4 = (t & 7) * 4;
    const float* wr = wsrc + (size_t)co * (C_ * K_);
    float acc0 = 0.f, acc1 = 0.f, acc2 = 0.f, acc3 = 0.f;
    for (int ci = 0; ci < C_; ci++) {
        float wk[K_];
        #pragma unroll
        for (int k = 0; k < K_; k++) wk[k] = wr[ci * K_ + k];
        float xv[12];
        float4 a = *(const float4*)&XsF[ci][w4];
        float4 bq = *(const float4*)&XsF[ci][w4 + 4];
        float4 c = *(const float4*)&XsF[ci][w4 + 8];
        xv[0]=a.x; xv[1]=a.y; xv[2]=a.z; xv[3]=a.w;
        xv[4]=bq.x; xv[5]=bq.y; xv[6]=bq.z; xv[7]=bq.w;
        xv[8]=c.x; xv[9]=c.y; xv[10]=c.z; xv[11]=c.w;
        #pragma unroll
        for (int k = 0; k < K_; k++) {
            acc0 = fmaf(wk[k], xv[k],     acc0);
            acc1 = fmaf(wk[k], xv[k + 1], acc1);
            acc2 = fmaf(wk[k], xv[k + 2], acc2);
            acc3 = fmaf(wk[k], xv[k + 3], acc3);
        }
    }
    const float bb = bias[co];
    const size_t obase = (((size_t)n * C_ + co) * H_ + h_out) * W_ + w0 + w4;
    float4 r = *(const float4*)&radd[obase];
    float4 o;
    o.x = fmaxf(acc0 + bb, 0.f) + r.x;
    o.y = fmaxf(acc1 + bb, 0.f) + r.y;
    o.z = fmaxf(acc2 + bb, 0.f) + r.z;
    o.w = fmaxf(acc3 + bb, 0.f) + r.w;
    *(float4*)&yout[obase] = o;
}

extern "C" void kernel_launch(void* const* d_in, const int* in_sizes, int n_in,
                              void* d_out, int out_size, void* d_ws, size_t ws_size,
                              hipStream_t stream) {
    const float* fea    = (const float*)d_in[0];
    const float* weight = (const float*)d_in[1];
    const float* bias   = (const float*)d_in[2];
    float* out = (float*)d_out;

    // ws: Wh | Wl | x0h | x0l | x1h | x1l | ctr(8 x 256B)
    const size_t need = (size_t)2 * WELEMS * 2 + (size_t)4 * XT_SZ * 2 + 2048;

    copy_row0<<<(N_ * C_ * W_ + 255) / 256, 256, 0, stream>>>(fea, out);

    if (ws_size >= need && d_ws != nullptr) {
        f16* wh  = (f16*)d_ws;
        f16* wl  = wh + WELEMS;
        f16* x0h = wl + WELEMS;
        f16* x0l = x0h + XT_SZ;
        f16* x1h = x0l + XT_SZ;
        f16* x1l = x1h + XT_SZ;
        unsigned* ctr = (unsigned*)(x1l + XT_SZ);

        hipMemsetAsync(ctr, 0, 2048, stream);
        prep_w<<<(WELEMS + 255) / 256, 256, 0, stream>>>(weight, wh, wl);
        prep_x0<<<(XT_SZ + 255) / 256, 256, 0, stream>>>(fea, x0h, x0l, x1h, x1l);

        hipFuncSetAttribute((const void*)conv_persist,
                            hipFuncAttributeMaxDynamicSharedMemorySize, LDS_BYTES);
        conv_persist<<<NBLK, 512, LDS_BYTES, stream>>>(x0h, x0l, x1h, x1l, wh, wl,
                                                       bias, fea, out, ctr);
    } else {
        for (int h = 1; h < H_; h++)
            step_f32<<<256, 256, 0, stream>>>(out, fea, out, weight, bias, h - 1, h);
        for (int h = H_ - 2; h >= 1; h--)
            step_f32<<<256, 256, 0, stream>>>(out, out, out, weight, bias, h + 1, h);
    }
}